// Round 9
// baseline (285.350 us; speedup 1.0000x reference)
//
#include <hip/hip_runtime.h>
#include <hip/hip_bf16.h>
#include <math.h>

#define NN 13
#define NC 26
#define VOC 10000
#define E 64
#define LAYERS 3
#define F 39
#define P 72            // S pitch (ushorts)
#define S_SZ (48 * P)   // 3456 ushorts = 6912 B

typedef float f32x4 __attribute__((ext_vector_type(4)));
typedef short s16x8 __attribute__((ext_vector_type(8)));

__device__ __forceinline__ ushort f2bf_rne(float f) {
    uint u = __builtin_bit_cast(uint, f);
    u = (u + 0x7fffu + ((u >> 16) & 1u)) >> 16;
    return (ushort)u;
}
__device__ __forceinline__ ushort fb(float f) {   // fuses to v_cvt_pk_bf16_f32
    return __builtin_bit_cast(ushort, __float2bfloat16(f));
}
__device__ __forceinline__ float bf2f(ushort h) {
    uint u = ((uint)h) << 16;
    return __builtin_bit_cast(float, u);
}
__device__ __forceinline__ uint pk2(float a, float b) {
    return (uint)fb(a) | ((uint)fb(b) << 16);
}
__device__ __forceinline__ s16x8 mk4(uint x, uint y, uint z, uint w) {
    uint4 u; u.x = x; u.y = y; u.z = z; u.w = w;
    return __builtin_bit_cast(s16x8, u);
}

// 4-lane-group transpose: D-frag (row=16*(mt)+4g+r, col=j) -> A/B-frag (idx=j, k=8g+i).
// pk[0]=mt_base, pk[1]=mt_base+1; effective mt = base + (g>>1).
__device__ __forceinline__ s16x8 tr2(const uint* pk, int s0l, int s1l, bool hi) {
    uint a0 = (uint)__shfl((int)pk[0], s0l), b0 = (uint)__shfl((int)pk[2], s0l);
    uint a1 = (uint)__shfl((int)pk[1], s0l), b1 = (uint)__shfl((int)pk[3], s0l);
    uint a2 = (uint)__shfl((int)pk[0], s1l), b2 = (uint)__shfl((int)pk[2], s1l);
    uint a3 = (uint)__shfl((int)pk[1], s1l), b3 = (uint)__shfl((int)pk[3], s1l);
    return mk4(hi ? b0 : a0, hi ? b1 : a1, hi ? b2 : a2, hi ? b3 : a3);
}
// same but the (g>=2) half has no source rows (keys 48..63): zero.
__device__ __forceinline__ s16x8 trz(const uint* pkm, int s0l, int s1l, bool hi) {
    uint a0 = (uint)__shfl((int)pkm[0], s0l);
    uint a1 = (uint)__shfl((int)pkm[1], s0l);
    uint a2 = (uint)__shfl((int)pkm[0], s1l);
    uint a3 = (uint)__shfl((int)pkm[1], s1l);
    return mk4(hi ? 0u : a0, hi ? 0u : a1, hi ? 0u : a2, hi ? 0u : a3);
}

// ---- one-shot fp32 -> bf16 weight conversion into d_ws ----
// ws layout (ushort): [WQ 3*4096][WK 3*4096][WV 3*4096][WO 3*4096][WR 3*4096]
__global__ void cvt_weights(const float* __restrict__ wq, const float* __restrict__ wk,
                            const float* __restrict__ wv, const float* __restrict__ wo,
                            const float* __restrict__ wr, ushort* __restrict__ outw) {
    int i = blockIdx.x * 256 + threadIdx.x;
    if (i >= 5 * 3 * 4096) return;
    int m = i / 12288, jj = i - m * 12288;
    const float* src = (m == 0) ? wq : (m == 1) ? wk : (m == 2) ? wv : (m == 3) ? wo : wr;
    outw[i] = f2bf_rne(src[jj]);
}

__global__ __launch_bounds__(64, 3) void autoint_mfma(
    const float* __restrict__ num, const int* __restrict__ cat,
    const float* __restrict__ Wnum, const float* __restrict__ bnum,
    const float* __restrict__ tabs, const ushort* __restrict__ wsw,
    const float* __restrict__ Wf, const float* __restrict__ bfin,
    float* __restrict__ out)
{
    __shared__ __align__(16) ushort S[S_SZ];   // embedding staging only

    const int l = threadIdx.x;
    const int j = l & 15;
    const int g = l >> 4;
    const int s = blockIdx.x;

    const int s0l = j + (((2 * g) & 3) << 4);       // shfl source lanes for tr2/trz
    const int s1l = j + (((2 * g + 1) & 3) << 4);
    const bool hi = g >= 2;

    // ---------------- embedding into S ----------------
    for (int f = 0; f < NN; ++f) {
        float v = num[s * NN + f];
        S[f * P + l] = fb(v * Wnum[f * E + l] + bnum[f * E + l]);
    }
    for (int c = 0; c < NC; ++c) {
        int idx = cat[s * NC + c];
        S[(NN + c) * P + l] = fb(tabs[((size_t)(c * VOC + idx)) * E + l]);
    }
    #pragma unroll
    for (int r = F; r < 48; ++r) S[r * P + l] = 0;
    __syncthreads();

    // x state: xf[nt][kt] = x[field 16nt+j][dim 8g+i+32kt]
    s16x8 xf[3][2];
    #pragma unroll
    for (int nt = 0; nt < 3; ++nt)
        #pragma unroll
        for (int kt = 0; kt < 2; ++kt)
            xf[nt][kt] = *(const s16x8*)&S[(j + 16 * nt) * P + 8 * g + 32 * kt];

    const float scale = 0.17677669529663687f; // 1/sqrt(32)

    for (int l3 = 0; l3 < LAYERS; ++l3) {
        const ushort* wq = wsw + 0 * 12288 + l3 * 4096;
        const ushort* wk = wsw + 1 * 12288 + l3 * 4096;
        const ushort* wv = wsw + 2 * 12288 + l3 * 4096;
        const ushort* wo = wsw + 3 * 12288 + l3 * 4096;
        const ushort* wr = wsw + 4 * 12288 + l3 * 4096;

        s16x8 qB[2][3], kA[2][3];

        // ---- Q^T = WQ @ x^T -> register transpose -> qB[h][nt] ----
        {
            f32x4 qa[4][3];
            #pragma unroll
            for (int mt = 0; mt < 4; ++mt)
                #pragma unroll
                for (int nt = 0; nt < 3; ++nt) qa[mt][nt] = (f32x4)0.f;
            #pragma unroll
            for (int kt = 0; kt < 2; ++kt)
                #pragma unroll
                for (int mt = 0; mt < 4; ++mt) {
                    s16x8 aq = *(const s16x8*)&wq[(j + 16 * mt) * E + 8 * g + 32 * kt];
                    #pragma unroll
                    for (int nt = 0; nt < 3; ++nt)
                        qa[mt][nt] = __builtin_amdgcn_mfma_f32_16x16x32_bf16(aq, xf[nt][kt], qa[mt][nt], 0, 0, 0);
                }
            #pragma unroll
            for (int nt = 0; nt < 3; ++nt) {
                uint pk[4][2];
                #pragma unroll
                for (int mt = 0; mt < 4; ++mt)
                    #pragma unroll
                    for (int rp = 0; rp < 2; ++rp)
                        pk[mt][rp] = pk2(qa[mt][nt][2 * rp], qa[mt][nt][2 * rp + 1]);
                qB[0][nt] = tr2(&pk[0][0], s0l, s1l, hi);
                qB[1][nt] = tr2(&pk[2][0], s0l, s1l, hi);
            }
        }

        // ---- K^T = WK @ x^T -> register transpose -> kA[h][t] ----
        {
            f32x4 ka[4][3];
            #pragma unroll
            for (int mt = 0; mt < 4; ++mt)
                #pragma unroll
                for (int nt = 0; nt < 3; ++nt) ka[mt][nt] = (f32x4)0.f;
            #pragma unroll
            for (int kt = 0; kt < 2; ++kt)
                #pragma unroll
                for (int mt = 0; mt < 4; ++mt) {
                    s16x8 ak = *(const s16x8*)&wk[(j + 16 * mt) * E + 8 * g + 32 * kt];
                    #pragma unroll
                    for (int nt = 0; nt < 3; ++nt)
                        ka[mt][nt] = __builtin_amdgcn_mfma_f32_16x16x32_bf16(ak, xf[nt][kt], ka[mt][nt], 0, 0, 0);
                }
            #pragma unroll
            for (int nt = 0; nt < 3; ++nt) {
                uint pk[4][2];
                #pragma unroll
                for (int mt = 0; mt < 4; ++mt)
                    #pragma unroll
                    for (int rp = 0; rp < 2; ++rp)
                        pk[mt][rp] = pk2(ka[mt][nt][2 * rp], ka[mt][nt][2 * rp + 1]);
                kA[0][nt] = tr2(&pk[0][0], s0l, s1l, hi);
                kA[1][nt] = tr2(&pk[2][0], s0l, s1l, hi);
            }
        }

        // ---- attention heads, fully in registers ----
        s16x8 ob[2][3];
        #pragma unroll
        for (int h = 0; h < 2; ++h) {
            s16x8 wvf[2][2];   // [kt][md]
            #pragma unroll
            for (int kt = 0; kt < 2; ++kt)
                #pragma unroll
                for (int md = 0; md < 2; ++md)
                    wvf[kt][md] = *(const s16x8*)&wv[(j + 16 * (2 * h + md)) * E + 8 * g + 32 * kt];

            // scores: S^T = K_h @ Q_h^T  (row=key 16mt+4g+r, col=query 16nt+j)
            f32x4 sc[3][3];
            #pragma unroll
            for (int mt = 0; mt < 3; ++mt)
                #pragma unroll
                for (int nt = 0; nt < 3; ++nt)
                    sc[mt][nt] = __builtin_amdgcn_mfma_f32_16x16x32_bf16(kA[h][mt], qB[h][nt], (f32x4)0.f, 0, 0, 0);

            // softmax over keys (raw max, scale folded; mask only mt==2)
            #pragma unroll
            for (int nt = 0; nt < 3; ++nt) {
                float mx = -1e30f;
                #pragma unroll
                for (int mt = 0; mt < 2; ++mt)
                    #pragma unroll
                    for (int r = 0; r < 4; ++r) mx = fmaxf(mx, sc[mt][nt][r]);
                #pragma unroll
                for (int r = 0; r < 4; ++r) {
                    int key = 32 + 4 * g + r;
                    float v = (key < F) ? sc[2][nt][r] : -1e30f;
                    sc[2][nt][r] = v;
                    mx = fmaxf(mx, v);
                }
                mx = fmaxf(mx, __shfl_xor(mx, 16));
                mx = fmaxf(mx, __shfl_xor(mx, 32));
                float mxs = mx * scale;
                float sum = 0.f;
                #pragma unroll
                for (int mt = 0; mt < 3; ++mt)
                    #pragma unroll
                    for (int r = 0; r < 4; ++r) {
                        float e = __expf(fmaf(sc[mt][nt][r], scale, -mxs));
                        sc[mt][nt][r] = e;
                        sum += e;
                    }
                sum += __shfl_xor(sum, 16);
                sum += __shfl_xor(sum, 32);
                float inv = 1.f / sum;
                #pragma unroll
                for (int mt = 0; mt < 3; ++mt)
                    #pragma unroll
                    for (int r = 0; r < 4; ++r) sc[mt][nt][r] *= inv;
            }

            // half-V: V = x @ WV^T (row=key 16mt+4g+r, col=dim 32h+16md+j)
            f32x4 va[3][2];
            #pragma unroll
            for (int mt = 0; mt < 3; ++mt)
                #pragma unroll
                for (int md = 0; md < 2; ++md) va[mt][md] = (f32x4)0.f;
            #pragma unroll
            for (int kt = 0; kt < 2; ++kt)
                #pragma unroll
                for (int md = 0; md < 2; ++md)
                    #pragma unroll
                    for (int mt = 0; mt < 3; ++mt)
                        va[mt][md] = __builtin_amdgcn_mfma_f32_16x16x32_bf16(xf[mt][kt], wvf[kt][md], va[mt][md], 0, 0, 0);

            // P transpose -> pb[kt][nt] (keys 48..63 = 0)
            s16x8 pb[2][3];
            #pragma unroll
            for (int nt = 0; nt < 3; ++nt) {
                uint pk[3][2];
                #pragma unroll
                for (int mt = 0; mt < 3; ++mt)
                    #pragma unroll
                    for (int rp = 0; rp < 2; ++rp)
                        pk[mt][rp] = pk2(sc[mt][nt][2 * rp], sc[mt][nt][2 * rp + 1]);
                pb[0][nt] = tr2(&pk[0][0], s0l, s1l, hi);
                pb[1][nt] = trz(&pk[2][0], s0l, s1l, hi);
            }
            // V transpose -> va2[md][kt] = V^T[dim 16md+j (in head)][key 8g+i+32kt]
            s16x8 va2[2][2];
            #pragma unroll
            for (int md = 0; md < 2; ++md) {
                uint pk[3][2];
                #pragma unroll
                for (int mt = 0; mt < 3; ++mt)
                    #pragma unroll
                    for (int rp = 0; rp < 2; ++rp)
                        pk[mt][rp] = pk2(va[mt][md][2 * rp], va[mt][md][2 * rp + 1]);
                va2[md][0] = tr2(&pk[0][0], s0l, s1l, hi);
                va2[md][1] = trz(&pk[2][0], s0l, s1l, hi);
            }

            // PV: out^T = V_h^T @ P_h^T  (row=dim-in-head 16md+4g+r, col=query 16nt+j)
            f32x4 oa[2][3];
            #pragma unroll
            for (int md = 0; md < 2; ++md)
                #pragma unroll
                for (int nt = 0; nt < 3; ++nt) oa[md][nt] = (f32x4)0.f;
            #pragma unroll
            for (int kt = 0; kt < 2; ++kt)
                #pragma unroll
                for (int md = 0; md < 2; ++md)
                    #pragma unroll
                    for (int nt = 0; nt < 3; ++nt)
                        oa[md][nt] = __builtin_amdgcn_mfma_f32_16x16x32_bf16(va2[md][kt], pb[kt][nt], oa[md][nt], 0, 0, 0);

            // Ot transpose -> ob[h][nt] = out^T[dim 32h+8g+i][query 16nt+j]
            #pragma unroll
            for (int nt = 0; nt < 3; ++nt) {
                uint pk[2][2];
                #pragma unroll
                for (int md = 0; md < 2; ++md)
                    #pragma unroll
                    for (int rp = 0; rp < 2; ++rp)
                        pk[md][rp] = pk2(oa[md][nt][2 * rp], oa[md][nt][2 * rp + 1]);
                ob[h][nt] = tr2(&pk[0][0], s0l, s1l, hi);
            }
        }

        // ---- x' = WO @ out^T + WR @ x^T -> register transpose -> new xf ----
        {
            f32x4 na[4][3];
            #pragma unroll
            for (int mt = 0; mt < 4; ++mt)
                #pragma unroll
                for (int nt = 0; nt < 3; ++nt) na[mt][nt] = (f32x4)0.f;
            #pragma unroll
            for (int kt = 0; kt < 2; ++kt)
                #pragma unroll
                for (int mt = 0; mt < 4; ++mt) {
                    s16x8 ao = *(const s16x8*)&wo[(j + 16 * mt) * E + 8 * g + 32 * kt];
                    #pragma unroll
                    for (int nt = 0; nt < 3; ++nt)
                        na[mt][nt] = __builtin_amdgcn_mfma_f32_16x16x32_bf16(ao, ob[kt][nt], na[mt][nt], 0, 0, 0);
                }
            #pragma unroll
            for (int kt = 0; kt < 2; ++kt)
                #pragma unroll
                for (int mt = 0; mt < 4; ++mt) {
                    s16x8 ar = *(const s16x8*)&wr[(j + 16 * mt) * E + 8 * g + 32 * kt];
                    #pragma unroll
                    for (int nt = 0; nt < 3; ++nt)
                        na[mt][nt] = __builtin_amdgcn_mfma_f32_16x16x32_bf16(ar, xf[nt][kt], na[mt][nt], 0, 0, 0);
                }
            #pragma unroll
            for (int nt = 0; nt < 3; ++nt) {
                uint pk[4][2];
                #pragma unroll
                for (int mt = 0; mt < 4; ++mt)
                    #pragma unroll
                    for (int rp = 0; rp < 2; ++rp)
                        pk[mt][rp] = pk2(na[mt][nt][2 * rp], na[mt][nt][2 * rp + 1]);
                xf[nt][0] = tr2(&pk[0][0], s0l, s1l, hi);
                xf[nt][1] = tr2(&pk[2][0], s0l, s1l, hi);
            }
        }
    }

    // ---------------- final linear + sigmoid (xf layout, full-wave reduce) ----------------
    float acc = 0.f;
    #pragma unroll
    for (int nt = 0; nt < 3; ++nt) {
        int f = 16 * nt + j;
        if (f < F) {
            #pragma unroll
            for (int kt = 0; kt < 2; ++kt) {
                const float* wp = Wf + f * E + 32 * kt + 8 * g;
                float4 wa = *(const float4*)wp;
                float4 wb = *(const float4*)(wp + 4);
                #pragma unroll
                for (int i = 0; i < 4; ++i)
                    acc += bf2f((ushort)xf[nt][kt][i]) * ((const float*)&wa)[i];
                #pragma unroll
                for (int i = 0; i < 4; ++i)
                    acc += bf2f((ushort)xf[nt][kt][4 + i]) * ((const float*)&wb)[i];
            }
        }
    }
    #pragma unroll
    for (int off = 1; off < 64; off <<= 1) acc += __shfl_xor(acc, off);
    if (l == 0) out[s] = 1.f / (1.f + __expf(-(acc + bfin[0])));
}

extern "C" void kernel_launch(void* const* d_in, const int* in_sizes, int n_in,
                              void* d_out, int out_size, void* d_ws, size_t ws_size,
                              hipStream_t stream) {
    ushort* wsb = (ushort*)d_ws;   // 61440 ushorts = 122880 B of scratch
    cvt_weights<<<240, 256, 0, stream>>>(
        (const float*)d_in[5], (const float*)d_in[6], (const float*)d_in[7],
        (const float*)d_in[8], (const float*)d_in[9], wsb);
    autoint_mfma<<<16384, 64, 0, stream>>>(
        (const float*)d_in[0], (const int*)d_in[1],
        (const float*)d_in[2], (const float*)d_in[3],
        (const float*)d_in[4], wsb,
        (const float*)d_in[10], (const float*)d_in[11],
        (float*)d_out);
}

// Round 10
// 255.574 us; speedup vs baseline: 1.1165x; 1.1165x over previous
//
#include <hip/hip_runtime.h>
#include <hip/hip_bf16.h>
#include <math.h>

#define NN 13
#define NC 26
#define VOC 10000
#define E 64
#define LAYERS 3
#define F 39
#define P 72    // S pitch (ushorts), 144B rows
#define VP 48   // Vh pitch (ushorts), 96B rows (16B-aligned)
#define VH_SZ (32 * VP)   // 1536 ushorts; kt=1 reads overrun into next row / S row 0 (finite, annihilated by Pt zeros)
#define S_SZ  (48 * P)    // 3456 ushorts

typedef float f32x4 __attribute__((ext_vector_type(4)));
typedef short s16x8 __attribute__((ext_vector_type(8)));

__device__ __forceinline__ ushort f2bf_rne(float f) {
    uint u = __builtin_bit_cast(uint, f);
    u = (u + 0x7fffu + ((u >> 16) & 1u)) >> 16;
    return (ushort)u;
}
__device__ __forceinline__ ushort fb(float f) {   // fuses to v_cvt_pk_bf16_f32
    return __builtin_bit_cast(ushort, __float2bfloat16(f));
}
__device__ __forceinline__ float bf2f(ushort h) {
    uint u = ((uint)h) << 16;
    return __builtin_bit_cast(float, u);
}
__device__ __forceinline__ void pack4(ushort* dst, f32x4 v) {
    ushort4 p;
    p.x = fb(v[0]); p.y = fb(v[1]); p.z = fb(v[2]); p.w = fb(v[3]);
    *(ushort4*)dst = p;
}

// ---- one-shot fp32 -> bf16 weight conversion into d_ws ----
// ws layout (ushort): [WQ 3*4096][WK 3*4096][WV 3*4096][WO 3*4096][WR 3*4096]
__global__ void cvt_weights(const float* __restrict__ wq, const float* __restrict__ wk,
                            const float* __restrict__ wv, const float* __restrict__ wo,
                            const float* __restrict__ wr, ushort* __restrict__ outw) {
    int i = blockIdx.x * 256 + threadIdx.x;
    if (i >= 5 * 3 * 4096) return;
    int m = i / 12288, jj = i - m * 12288;
    const float* src = (m == 0) ? wq : (m == 1) ? wk : (m == 2) ? wv : (m == 3) ? wo : wr;
    outw[i] = f2bf_rne(src[jj]);
}

__global__ __launch_bounds__(64, 4) void autoint_mfma(
    const float* __restrict__ num, const int* __restrict__ cat,
    const float* __restrict__ Wnum, const float* __restrict__ bnum,
    const float* __restrict__ tabs, const ushort* __restrict__ wsw,
    const float* __restrict__ Wf, const float* __restrict__ bfin,
    float* __restrict__ out)
{
    __shared__ __align__(16) ushort smem[VH_SZ + S_SZ];   // 9984 B total
    ushort* Vh = smem;           // [32][48] per-head half-V [dim-in-head][key]
    ushort* S  = smem + VH_SZ;   // [48][72] staging: x / Q / K / Pt / Ot / x'

    const int l = threadIdx.x;
    const int j = l & 15;
    const int g = l >> 4;
    const int s = blockIdx.x;

    ushort4 z4; z4.x = z4.y = z4.z = z4.w = 0;

    // ---------------- embedding into S ----------------
    for (int f = 0; f < NN; ++f) {
        float v = num[s * NN + f];
        S[f * P + l] = fb(v * Wnum[f * E + l] + bnum[f * E + l]);
    }
    for (int c = 0; c < NC; ++c) {
        int idx = cat[s * NC + c];
        S[(NN + c) * P + l] = fb(tabs[((size_t)(c * VOC + idx)) * E + l]);
    }
    #pragma unroll
    for (int r = F; r < 48; ++r) S[r * P + l] = 0;
    __syncthreads();

    // x fragments in registers: row j+16nt, dims 8g..8g+7 (+32kt)
    s16x8 xf[3][2];
    #pragma unroll
    for (int nt = 0; nt < 3; ++nt)
        #pragma unroll
        for (int kt = 0; kt < 2; ++kt)
            xf[nt][kt] = *(const s16x8*)&S[(j + 16 * nt) * P + 8 * g + 32 * kt];

    const float scale = 0.17677669529663687f; // 1/sqrt(32)

    for (int l3 = 0; l3 < LAYERS; ++l3) {
        const ushort* wq = wsw + 0 * 12288 + l3 * 4096;
        const ushort* wk = wsw + 1 * 12288 + l3 * 4096;
        const ushort* wv = wsw + 2 * 12288 + l3 * 4096;
        const ushort* wo = wsw + 3 * 12288 + l3 * 4096;
        const ushort* wr = wsw + 4 * 12288 + l3 * 4096;

        // ---- Q^T = WQ @ x^T -> stage in S -> qB frags (both heads) ----
        s16x8 qB[2][3];
        {
            f32x4 qa[4][3];
            #pragma unroll
            for (int mt = 0; mt < 4; ++mt)
                #pragma unroll
                for (int nt = 0; nt < 3; ++nt) qa[mt][nt] = (f32x4)0.f;
            #pragma unroll
            for (int kt = 0; kt < 2; ++kt)
                #pragma unroll
                for (int mt = 0; mt < 4; ++mt) {
                    s16x8 aq = *(const s16x8*)&wq[(j + 16 * mt) * E + 8 * g + 32 * kt];
                    #pragma unroll
                    for (int nt = 0; nt < 3; ++nt)
                        qa[mt][nt] = __builtin_amdgcn_mfma_f32_16x16x32_bf16(aq, xf[nt][kt], qa[mt][nt], 0, 0, 0);
                }
            __syncthreads();   // xf LDS reads complete before overwrite
            #pragma unroll
            for (int mt = 0; mt < 4; ++mt)
                #pragma unroll
                for (int nt = 0; nt < 3; ++nt)
                    pack4(&S[(j + 16 * nt) * P + 16 * mt + 4 * g], qa[mt][nt]);  // Q[field][dim]
            __syncthreads();
            #pragma unroll
            for (int h = 0; h < 2; ++h)
                #pragma unroll
                for (int t = 0; t < 3; ++t)
                    qB[h][t] = *(const s16x8*)&S[(j + 16 * t) * P + 32 * h + 8 * g];
            __syncthreads();
        }

        // ---- K^T = WK @ x^T -> stage in S ----
        {
            f32x4 ka[4][3];
            #pragma unroll
            for (int mt = 0; mt < 4; ++mt)
                #pragma unroll
                for (int nt = 0; nt < 3; ++nt) ka[mt][nt] = (f32x4)0.f;
            #pragma unroll
            for (int kt = 0; kt < 2; ++kt)
                #pragma unroll
                for (int mt = 0; mt < 4; ++mt) {
                    s16x8 ak = *(const s16x8*)&wk[(j + 16 * mt) * E + 8 * g + 32 * kt];
                    #pragma unroll
                    for (int nt = 0; nt < 3; ++nt)
                        ka[mt][nt] = __builtin_amdgcn_mfma_f32_16x16x32_bf16(ak, xf[nt][kt], ka[mt][nt], 0, 0, 0);
                }
            #pragma unroll
            for (int mt = 0; mt < 4; ++mt)
                #pragma unroll
                for (int nt = 0; nt < 3; ++nt)
                    pack4(&S[(j + 16 * nt) * P + 16 * mt + 4 * g], ka[mt][nt]);  // K[field][dim]
            __syncthreads();
        }

        // ---- K fragments for BOTH heads (before S is overwritten by Pt) ----
        s16x8 kA[2][3];
        #pragma unroll
        for (int h = 0; h < 2; ++h)
            #pragma unroll
            for (int t = 0; t < 3; ++t)
                kA[h][t] = *(const s16x8*)&S[(j + 16 * t) * P + 32 * h + 8 * g];
        __syncthreads();

        f32x4 oa[2][2][3];   // [h][md][nt]
        #pragma unroll
        for (int h = 0; h < 2; ++h) {
            // ---- issue this head's WV frag loads early (covered by scores+softmax) ----
            s16x8 wvf[2][2];   // [kt][md]
            #pragma unroll
            for (int kt = 0; kt < 2; ++kt)
                #pragma unroll
                for (int md = 0; md < 2; ++md)
                    wvf[kt][md] = *(const s16x8*)&wv[(j + 16 * (2 * h + md)) * E + 8 * g + 32 * kt];

            // ---- scores: S^T = K_h @ Q_h^T ----
            f32x4 sc[3][3];
            #pragma unroll
            for (int mt = 0; mt < 3; ++mt)
                #pragma unroll
                for (int nt = 0; nt < 3; ++nt)
                    sc[mt][nt] = __builtin_amdgcn_mfma_f32_16x16x32_bf16(kA[h][mt], qB[h][nt], (f32x4)0.f, 0, 0, 0);

            // ---- softmax over keys (raw-max, scale folded into exp arg; mask only mt==2) ----
            #pragma unroll
            for (int nt = 0; nt < 3; ++nt) {
                float mx = -1e30f;
                #pragma unroll
                for (int mt = 0; mt < 2; ++mt)
                    #pragma unroll
                    for (int r = 0; r < 4; ++r) mx = fmaxf(mx, sc[mt][nt][r]);
                #pragma unroll
                for (int r = 0; r < 4; ++r) {
                    int key = 32 + 4 * g + r;
                    float v = (key < F) ? sc[2][nt][r] : -1e30f;
                    sc[2][nt][r] = v;
                    mx = fmaxf(mx, v);
                }
                mx = fmaxf(mx, __shfl_xor(mx, 16));
                mx = fmaxf(mx, __shfl_xor(mx, 32));
                float mxs = mx * scale;
                float sum = 0.f;
                #pragma unroll
                for (int mt = 0; mt < 3; ++mt)
                    #pragma unroll
                    for (int r = 0; r < 4; ++r) {
                        float e = __expf(fmaf(sc[mt][nt][r], scale, -mxs));
                        sc[mt][nt][r] = e;
                        sum += e;
                    }
                sum += __shfl_xor(sum, 16);
                sum += __shfl_xor(sum, 32);
                float inv = 1.f / sum;
                #pragma unroll
                for (int mt = 0; mt < 3; ++mt)
                    #pragma unroll
                    for (int r = 0; r < 4; ++r) sc[mt][nt][r] *= inv;
            }

            // ---- this head's half-V: V = x @ WV^T (after softmax -> wvf loads covered) ----
            f32x4 va[3][2];
            #pragma unroll
            for (int mt = 0; mt < 3; ++mt)
                #pragma unroll
                for (int md = 0; md < 2; ++md) va[mt][md] = (f32x4)0.f;
            #pragma unroll
            for (int kt = 0; kt < 2; ++kt)
                #pragma unroll
                for (int md = 0; md < 2; ++md)
                    #pragma unroll
                    for (int mt = 0; mt < 3; ++mt)
                        va[mt][md] = __builtin_amdgcn_mfma_f32_16x16x32_bf16(xf[mt][kt], wvf[kt][md], va[mt][md], 0, 0, 0);

            // ---- stage Pt (zero key-pad 48..63) + this head's half-V ----
            #pragma unroll
            for (int nt = 0; nt < 3; ++nt) {
                #pragma unroll
                for (int mt = 0; mt < 3; ++mt)
                    pack4(&S[(16 * nt + j) * P + 16 * mt + 4 * g], sc[mt][nt]);
                *(ushort4*)&S[(16 * nt + j) * P + 48 + 4 * g] = z4;
            }
            #pragma unroll
            for (int md = 0; md < 2; ++md)
                #pragma unroll
                for (int mt = 0; mt < 3; ++mt)
                    pack4(&Vh[(j + 16 * md) * VP + 16 * mt + 4 * g], va[mt][md]);  // Vh[dim-in-head][key]
            __syncthreads();

            // ---- pb read, PV: out^T = V_h^T @ P_h^T ----
            // va2 kt=1 reads overrun Vh row ends into the next row / S row 0 (always freshly
            // written finite data this phase); garbage keys 48..63 are annihilated by pb zeros.
            s16x8 pb[2][3];
            #pragma unroll
            for (int kt = 0; kt < 2; ++kt)
                #pragma unroll
                for (int nt = 0; nt < 3; ++nt)
                    pb[kt][nt] = *(const s16x8*)&S[(j + 16 * nt) * P + 8 * g + 32 * kt];
            #pragma unroll
            for (int md = 0; md < 2; ++md)
                #pragma unroll
                for (int nt = 0; nt < 3; ++nt) oa[h][md][nt] = (f32x4)0.f;
            #pragma unroll
            for (int kt = 0; kt < 2; ++kt)
                #pragma unroll
                for (int md = 0; md < 2; ++md) {
                    s16x8 va2 = *(const s16x8*)&Vh[(j + 16 * md) * VP + 8 * g + 32 * kt];
                    #pragma unroll
                    for (int nt = 0; nt < 3; ++nt)
                        oa[h][md][nt] = __builtin_amdgcn_mfma_f32_16x16x32_bf16(va2, pb[kt][nt], oa[h][md][nt], 0, 0, 0);
                }
            __syncthreads();   // S + Vh reads done before next h overwrites
        }

        // ---- stage Ot[q][dim] (both heads) ----
        #pragma unroll
        for (int h = 0; h < 2; ++h)
            #pragma unroll
            for (int md = 0; md < 2; ++md)
                #pragma unroll
                for (int nt = 0; nt < 3; ++nt)
                    pack4(&S[(16 * nt + j) * P + 32 * h + 16 * md + 4 * g], oa[h][md][nt]);
        __syncthreads();

        // ---- next x^T = WO @ out^T + WR @ x^T ----
        {
            s16x8 ob[2][3];
            #pragma unroll
            for (int kt = 0; kt < 2; ++kt)
                #pragma unroll
                for (int nt = 0; nt < 3; ++nt)
                    ob[kt][nt] = *(const s16x8*)&S[(j + 16 * nt) * P + 8 * g + 32 * kt];

            f32x4 na[4][3];
            #pragma unroll
            for (int mt = 0; mt < 4; ++mt)
                #pragma unroll
                for (int nt = 0; nt < 3; ++nt) na[mt][nt] = (f32x4)0.f;
            #pragma unroll
            for (int kt = 0; kt < 2; ++kt)
                #pragma unroll
                for (int mt = 0; mt < 4; ++mt) {
                    s16x8 ao = *(const s16x8*)&wo[(j + 16 * mt) * E + 8 * g + 32 * kt];
                    #pragma unroll
                    for (int nt = 0; nt < 3; ++nt)
                        na[mt][nt] = __builtin_amdgcn_mfma_f32_16x16x32_bf16(ao, ob[kt][nt], na[mt][nt], 0, 0, 0);
                }
            #pragma unroll
            for (int kt = 0; kt < 2; ++kt)
                #pragma unroll
                for (int mt = 0; mt < 4; ++mt) {
                    s16x8 ar = *(const s16x8*)&wr[(j + 16 * mt) * E + 8 * g + 32 * kt];
                    #pragma unroll
                    for (int nt = 0; nt < 3; ++nt)
                        na[mt][nt] = __builtin_amdgcn_mfma_f32_16x16x32_bf16(ar, xf[nt][kt], na[mt][nt], 0, 0, 0);
                }
            __syncthreads();
            #pragma unroll
            for (int mt = 0; mt < 4; ++mt)
                #pragma unroll
                for (int nt = 0; nt < 3; ++nt)
                    pack4(&S[(16 * nt + j) * P + 16 * mt + 4 * g], na[mt][nt]);  // x'[field][dim]
            __syncthreads();
            #pragma unroll
            for (int nt = 0; nt < 3; ++nt)
                #pragma unroll
                for (int kt = 0; kt < 2; ++kt)
                    xf[nt][kt] = *(const s16x8*)&S[(j + 16 * nt) * P + 8 * g + 32 * kt];
        }
    }

    // ---------------- final linear + sigmoid ----------------
    float acc = 0.f;
    for (int f = 0; f < F; ++f)
        acc += bf2f(S[f * P + l]) * Wf[f * E + l];
    #pragma unroll
    for (int off = 32; off > 0; off >>= 1) acc += __shfl_down(acc, off);
    if (l == 0) out[s] = 1.f / (1.f + __expf(-(acc + bfin[0])));
}

extern "C" void kernel_launch(void* const* d_in, const int* in_sizes, int n_in,
                              void* d_out, int out_size, void* d_ws, size_t ws_size,
                              hipStream_t stream) {
    ushort* wsb = (ushort*)d_ws;   // 61440 ushorts = 122880 B of scratch
    cvt_weights<<<240, 256, 0, stream>>>(
        (const float*)d_in[5], (const float*)d_in[6], (const float*)d_in[7],
        (const float*)d_in[8], (const float*)d_in[9], wsb);
    autoint_mfma<<<16384, 64, 0, stream>>>(
        (const float*)d_in[0], (const int*)d_in[1],
        (const float*)d_in[2], (const float*)d_in[3],
        (const float*)d_in[4], wsb,
        (const float*)d_in[10], (const float*)d_in[11],
        (float*)d_out);
}

// Round 11
// 220.384 us; speedup vs baseline: 1.2948x; 1.1597x over previous
//
#include <hip/hip_runtime.h>
#include <hip/hip_bf16.h>
#include <math.h>

#define NN 13
#define NC 26
#define VOC 10000
#define E 64
#define LAYERS 3
#define F 39
#define P 72    // S pitch (ushorts), 144B rows
#define VP 48   // Vh pitch (ushorts), 96B rows
#define VH_SZ (32 * VP)       // 1536 ushorts
#define S_SZ  (48 * P)        // 3456 ushorts
#define SAMP  (VH_SZ + S_SZ)  // 4992 ushorts = 9984 B per sample

typedef float f32x4 __attribute__((ext_vector_type(4)));
typedef short s16x8 __attribute__((ext_vector_type(8)));

__device__ __forceinline__ ushort f2bf_rne(float f) {
    uint u = __builtin_bit_cast(uint, f);
    u = (u + 0x7fffu + ((u >> 16) & 1u)) >> 16;
    return (ushort)u;
}
__device__ __forceinline__ ushort fb(float f) {   // fuses to v_cvt_pk_bf16_f32
    return __builtin_bit_cast(ushort, __float2bfloat16(f));
}
__device__ __forceinline__ float bf2f(ushort h) {
    uint u = ((uint)h) << 16;
    return __builtin_bit_cast(float, u);
}
__device__ __forceinline__ void pack4(ushort* dst, f32x4 v) {
    ushort4 p;
    p.x = fb(v[0]); p.y = fb(v[1]); p.z = fb(v[2]); p.w = fb(v[3]);
    *(ushort4*)dst = p;
}

// ---- one-shot fp32 -> bf16 weight conversion into d_ws ----
// ws layout (ushort): [WQ 3*4096][WK 3*4096][WV 3*4096][WO 3*4096][WR 3*4096]
__global__ void cvt_weights(const float* __restrict__ wq, const float* __restrict__ wk,
                            const float* __restrict__ wv, const float* __restrict__ wo,
                            const float* __restrict__ wr, ushort* __restrict__ outw) {
    int i = blockIdx.x * 256 + threadIdx.x;
    if (i >= 5 * 3 * 4096) return;
    int m = i / 12288, jj = i - m * 12288;
    const float* src = (m == 0) ? wq : (m == 1) ? wk : (m == 2) ? wv : (m == 3) ? wo : wr;
    outw[i] = f2bf_rne(src[jj]);
}

// Per-sample LDS: [Vh 32x48][S 48x72]; Vh kt=1 reads overrun into next row / S row 0
// (always freshly-written finite data; garbage key-slots annihilated by Pt zero columns).
__global__ __launch_bounds__(64, 2) void autoint_mfma(
    const float* __restrict__ num, const int* __restrict__ cat,
    const float* __restrict__ Wnum, const float* __restrict__ bnum,
    const float* __restrict__ tabs, const ushort* __restrict__ wsw,
    const float* __restrict__ Wf, const float* __restrict__ bfin,
    float* __restrict__ out)
{
    __shared__ __align__(16) ushort smem[2 * SAMP];   // 19968 B -> 8 blocks/CU

    const int l = threadIdx.x;
    const int j = l & 15;
    const int g = l >> 4;
    const long s0 = 2 * (long)blockIdx.x;
    const long s1 = s0 + 1;

    ushort4 z4; z4.x = z4.y = z4.z = z4.w = 0;

    // ---------------- embedding (weights shared across the 2 samples) ----------------
    for (int f = 0; f < NN; ++f) {
        float wn = Wnum[f * E + l], bn = bnum[f * E + l];
        smem[VH_SZ + f * P + l]        = fb(num[s0 * NN + f] * wn + bn);
        smem[SAMP + VH_SZ + f * P + l] = fb(num[s1 * NN + f] * wn + bn);
    }
    for (int c = 0; c < NC; ++c) {
        int ia = cat[s0 * NC + c], ib = cat[s1 * NC + c];
        smem[VH_SZ + (NN + c) * P + l]        = fb(tabs[((size_t)(c * VOC + ia)) * E + l]);
        smem[SAMP + VH_SZ + (NN + c) * P + l] = fb(tabs[((size_t)(c * VOC + ib)) * E + l]);
    }
    #pragma unroll
    for (int r = F; r < 48; ++r) {
        smem[VH_SZ + r * P + l] = 0;
        smem[SAMP + VH_SZ + r * P + l] = 0;
    }
    __syncthreads();

    // x fragments, both samples: xf[sp][nt][kt] = x[field 16nt+j][dim 8g+i+32kt]
    s16x8 xf[2][3][2];
    #pragma unroll
    for (int sp = 0; sp < 2; ++sp)
        #pragma unroll
        for (int nt = 0; nt < 3; ++nt)
            #pragma unroll
            for (int kt = 0; kt < 2; ++kt)
                xf[sp][nt][kt] = *(const s16x8*)&smem[sp * SAMP + VH_SZ + (j + 16 * nt) * P + 8 * g + 32 * kt];

    const float scale = 0.17677669529663687f; // 1/sqrt(32)

    for (int l3 = 0; l3 < LAYERS; ++l3) {
        const ushort* wq = wsw + 0 * 12288 + l3 * 4096;
        const ushort* wk = wsw + 1 * 12288 + l3 * 4096;
        const ushort* wv = wsw + 2 * 12288 + l3 * 4096;
        const ushort* wo = wsw + 3 * 12288 + l3 * 4096;
        const ushort* wr = wsw + 4 * 12288 + l3 * 4096;

        // ---- Q^T = WQ @ x^T (both samples, shared weight frags) -> stage -> qB ----
        s16x8 qB[2][2][3];   // [sp][h][t]
        {
            f32x4 qa[2][4][3];
            #pragma unroll
            for (int sp = 0; sp < 2; ++sp)
                #pragma unroll
                for (int mt = 0; mt < 4; ++mt)
                    #pragma unroll
                    for (int nt = 0; nt < 3; ++nt) qa[sp][mt][nt] = (f32x4)0.f;
            #pragma unroll
            for (int kt = 0; kt < 2; ++kt)
                #pragma unroll
                for (int mt = 0; mt < 4; ++mt) {
                    s16x8 aq = *(const s16x8*)&wq[(j + 16 * mt) * E + 8 * g + 32 * kt];
                    #pragma unroll
                    for (int sp = 0; sp < 2; ++sp)
                        #pragma unroll
                        for (int nt = 0; nt < 3; ++nt)
                            qa[sp][mt][nt] = __builtin_amdgcn_mfma_f32_16x16x32_bf16(aq, xf[sp][nt][kt], qa[sp][mt][nt], 0, 0, 0);
                }
            __syncthreads();
            #pragma unroll
            for (int sp = 0; sp < 2; ++sp)
                #pragma unroll
                for (int mt = 0; mt < 4; ++mt)
                    #pragma unroll
                    for (int nt = 0; nt < 3; ++nt)
                        pack4(&smem[sp * SAMP + VH_SZ + (j + 16 * nt) * P + 16 * mt + 4 * g], qa[sp][mt][nt]);
            __syncthreads();
            #pragma unroll
            for (int sp = 0; sp < 2; ++sp)
                #pragma unroll
                for (int h = 0; h < 2; ++h)
                    #pragma unroll
                    for (int t = 0; t < 3; ++t)
                        qB[sp][h][t] = *(const s16x8*)&smem[sp * SAMP + VH_SZ + (j + 16 * t) * P + 32 * h + 8 * g];
            __syncthreads();
        }

        // ---- K^T = WK @ x^T -> stage -> kA ----
        s16x8 kA[2][2][3];   // [sp][h][t]
        {
            f32x4 ka[2][4][3];
            #pragma unroll
            for (int sp = 0; sp < 2; ++sp)
                #pragma unroll
                for (int mt = 0; mt < 4; ++mt)
                    #pragma unroll
                    for (int nt = 0; nt < 3; ++nt) ka[sp][mt][nt] = (f32x4)0.f;
            #pragma unroll
            for (int kt = 0; kt < 2; ++kt)
                #pragma unroll
                for (int mt = 0; mt < 4; ++mt) {
                    s16x8 ak = *(const s16x8*)&wk[(j + 16 * mt) * E + 8 * g + 32 * kt];
                    #pragma unroll
                    for (int sp = 0; sp < 2; ++sp)
                        #pragma unroll
                        for (int nt = 0; nt < 3; ++nt)
                            ka[sp][mt][nt] = __builtin_amdgcn_mfma_f32_16x16x32_bf16(ak, xf[sp][nt][kt], ka[sp][mt][nt], 0, 0, 0);
                }
            #pragma unroll
            for (int sp = 0; sp < 2; ++sp)
                #pragma unroll
                for (int mt = 0; mt < 4; ++mt)
                    #pragma unroll
                    for (int nt = 0; nt < 3; ++nt)
                        pack4(&smem[sp * SAMP + VH_SZ + (j + 16 * nt) * P + 16 * mt + 4 * g], ka[sp][mt][nt]);
            __syncthreads();
            #pragma unroll
            for (int sp = 0; sp < 2; ++sp)
                #pragma unroll
                for (int h = 0; h < 2; ++h)
                    #pragma unroll
                    for (int t = 0; t < 3; ++t)
                        kA[sp][h][t] = *(const s16x8*)&smem[sp * SAMP + VH_SZ + (j + 16 * t) * P + 32 * h + 8 * g];
            __syncthreads();
        }

        f32x4 oa[2][2][2][3];   // [sp][h][md][nt]
        #pragma unroll
        for (int h = 0; h < 2; ++h) {
            // this head's WV frags (shared across samples), issued early
            s16x8 wvf[2][2];   // [kt][md]
            #pragma unroll
            for (int kt = 0; kt < 2; ++kt)
                #pragma unroll
                for (int md = 0; md < 2; ++md)
                    wvf[kt][md] = *(const s16x8*)&wv[(j + 16 * (2 * h + md)) * E + 8 * g + 32 * kt];

            // scores: S^T = K_h @ Q_h^T
            f32x4 sc[2][3][3];
            #pragma unroll
            for (int sp = 0; sp < 2; ++sp)
                #pragma unroll
                for (int mt = 0; mt < 3; ++mt)
                    #pragma unroll
                    for (int nt = 0; nt < 3; ++nt)
                        sc[sp][mt][nt] = __builtin_amdgcn_mfma_f32_16x16x32_bf16(kA[sp][h][mt], qB[sp][h][nt], (f32x4)0.f, 0, 0, 0);

            // softmax over keys (raw max, scale folded; mask only mt==2)
            #pragma unroll
            for (int sp = 0; sp < 2; ++sp)
                #pragma unroll
                for (int nt = 0; nt < 3; ++nt) {
                    float mx = -1e30f;
                    #pragma unroll
                    for (int mt = 0; mt < 2; ++mt)
                        #pragma unroll
                        for (int r = 0; r < 4; ++r) mx = fmaxf(mx, sc[sp][mt][nt][r]);
                    #pragma unroll
                    for (int r = 0; r < 4; ++r) {
                        int key = 32 + 4 * g + r;
                        float v = (key < F) ? sc[sp][2][nt][r] : -1e30f;
                        sc[sp][2][nt][r] = v;
                        mx = fmaxf(mx, v);
                    }
                    mx = fmaxf(mx, __shfl_xor(mx, 16));
                    mx = fmaxf(mx, __shfl_xor(mx, 32));
                    float mxs = mx * scale;
                    float sum = 0.f;
                    #pragma unroll
                    for (int mt = 0; mt < 3; ++mt)
                        #pragma unroll
                        for (int r = 0; r < 4; ++r) {
                            float e = __expf(fmaf(sc[sp][mt][nt][r], scale, -mxs));
                            sc[sp][mt][nt][r] = e;
                            sum += e;
                        }
                    sum += __shfl_xor(sum, 16);
                    sum += __shfl_xor(sum, 32);
                    float inv = 1.f / sum;
                    #pragma unroll
                    for (int mt = 0; mt < 3; ++mt)
                        #pragma unroll
                        for (int r = 0; r < 4; ++r) sc[sp][mt][nt][r] *= inv;
                }

            // this head's half-V: V = x @ WV^T
            f32x4 va[2][3][2];
            #pragma unroll
            for (int sp = 0; sp < 2; ++sp)
                #pragma unroll
                for (int mt = 0; mt < 3; ++mt)
                    #pragma unroll
                    for (int md = 0; md < 2; ++md) va[sp][mt][md] = (f32x4)0.f;
            #pragma unroll
            for (int kt = 0; kt < 2; ++kt)
                #pragma unroll
                for (int md = 0; md < 2; ++md)
                    #pragma unroll
                    for (int sp = 0; sp < 2; ++sp)
                        #pragma unroll
                        for (int mt = 0; mt < 3; ++mt)
                            va[sp][mt][md] = __builtin_amdgcn_mfma_f32_16x16x32_bf16(xf[sp][mt][kt], wvf[kt][md], va[sp][mt][md], 0, 0, 0);

            // stage Pt (zero key-pad 48..63) + half-V
            #pragma unroll
            for (int sp = 0; sp < 2; ++sp) {
                #pragma unroll
                for (int nt = 0; nt < 3; ++nt) {
                    #pragma unroll
                    for (int mt = 0; mt < 3; ++mt)
                        pack4(&smem[sp * SAMP + VH_SZ + (16 * nt + j) * P + 16 * mt + 4 * g], sc[sp][mt][nt]);
                    *(ushort4*)&smem[sp * SAMP + VH_SZ + (16 * nt + j) * P + 48 + 4 * g] = z4;
                }
                #pragma unroll
                for (int md = 0; md < 2; ++md)
                    #pragma unroll
                    for (int mt = 0; mt < 3; ++mt)
                        pack4(&smem[sp * SAMP + (j + 16 * md) * VP + 16 * mt + 4 * g], va[sp][mt][md]);
            }
            __syncthreads();

            // pb read, PV: out^T = V_h^T @ P_h^T
            s16x8 pb[2][2][3];   // [sp][kt][nt]
            #pragma unroll
            for (int sp = 0; sp < 2; ++sp)
                #pragma unroll
                for (int kt = 0; kt < 2; ++kt)
                    #pragma unroll
                    for (int nt = 0; nt < 3; ++nt)
                        pb[sp][kt][nt] = *(const s16x8*)&smem[sp * SAMP + VH_SZ + (j + 16 * nt) * P + 8 * g + 32 * kt];
            #pragma unroll
            for (int sp = 0; sp < 2; ++sp)
                #pragma unroll
                for (int md = 0; md < 2; ++md)
                    #pragma unroll
                    for (int nt = 0; nt < 3; ++nt) oa[sp][h][md][nt] = (f32x4)0.f;
            #pragma unroll
            for (int kt = 0; kt < 2; ++kt)
                #pragma unroll
                for (int sp = 0; sp < 2; ++sp)
                    #pragma unroll
                    for (int md = 0; md < 2; ++md) {
                        s16x8 va2 = *(const s16x8*)&smem[sp * SAMP + (j + 16 * md) * VP + 8 * g + 32 * kt];
                        #pragma unroll
                        for (int nt = 0; nt < 3; ++nt)
                            oa[sp][h][md][nt] = __builtin_amdgcn_mfma_f32_16x16x32_bf16(va2, pb[sp][kt][nt], oa[sp][h][md][nt], 0, 0, 0);
                    }
            __syncthreads();   // S + Vh reads done before next h overwrites
        }

        // ---- stage Ot[q][dim] (both samples, both heads) ----
        #pragma unroll
        for (int sp = 0; sp < 2; ++sp)
            #pragma unroll
            for (int h = 0; h < 2; ++h)
                #pragma unroll
                for (int md = 0; md < 2; ++md)
                    #pragma unroll
                    for (int nt = 0; nt < 3; ++nt)
                        pack4(&smem[sp * SAMP + VH_SZ + (16 * nt + j) * P + 32 * h + 16 * md + 4 * g], oa[sp][h][md][nt]);
        __syncthreads();

        // ---- next x^T = WO @ out^T + WR @ x^T ----
        {
            s16x8 ob[2][2][3];   // [sp][kt][nt]
            #pragma unroll
            for (int sp = 0; sp < 2; ++sp)
                #pragma unroll
                for (int kt = 0; kt < 2; ++kt)
                    #pragma unroll
                    for (int nt = 0; nt < 3; ++nt)
                        ob[sp][kt][nt] = *(const s16x8*)&smem[sp * SAMP + VH_SZ + (j + 16 * nt) * P + 8 * g + 32 * kt];

            f32x4 na[2][4][3];
            #pragma unroll
            for (int sp = 0; sp < 2; ++sp)
                #pragma unroll
                for (int mt = 0; mt < 4; ++mt)
                    #pragma unroll
                    for (int nt = 0; nt < 3; ++nt) na[sp][mt][nt] = (f32x4)0.f;
            #pragma unroll
            for (int kt = 0; kt < 2; ++kt)
                #pragma unroll
                for (int mt = 0; mt < 4; ++mt) {
                    s16x8 ao = *(const s16x8*)&wo[(j + 16 * mt) * E + 8 * g + 32 * kt];
                    #pragma unroll
                    for (int sp = 0; sp < 2; ++sp)
                        #pragma unroll
                        for (int nt = 0; nt < 3; ++nt)
                            na[sp][mt][nt] = __builtin_amdgcn_mfma_f32_16x16x32_bf16(ao, ob[sp][kt][nt], na[sp][mt][nt], 0, 0, 0);
                }
            #pragma unroll
            for (int kt = 0; kt < 2; ++kt)
                #pragma unroll
                for (int mt = 0; mt < 4; ++mt) {
                    s16x8 ar = *(const s16x8*)&wr[(j + 16 * mt) * E + 8 * g + 32 * kt];
                    #pragma unroll
                    for (int sp = 0; sp < 2; ++sp)
                        #pragma unroll
                        for (int nt = 0; nt < 3; ++nt)
                            na[sp][mt][nt] = __builtin_amdgcn_mfma_f32_16x16x32_bf16(ar, xf[sp][nt][kt], na[sp][mt][nt], 0, 0, 0);
                }
            __syncthreads();
            #pragma unroll
            for (int sp = 0; sp < 2; ++sp)
                #pragma unroll
                for (int mt = 0; mt < 4; ++mt)
                    #pragma unroll
                    for (int nt = 0; nt < 3; ++nt)
                        pack4(&smem[sp * SAMP + VH_SZ + (16 * nt + j) * P + 16 * mt + 4 * g], na[sp][mt][nt]);
            __syncthreads();
            #pragma unroll
            for (int sp = 0; sp < 2; ++sp)
                #pragma unroll
                for (int nt = 0; nt < 3; ++nt)
                    #pragma unroll
                    for (int kt = 0; kt < 2; ++kt)
                        xf[sp][nt][kt] = *(const s16x8*)&smem[sp * SAMP + VH_SZ + (j + 16 * nt) * P + 8 * g + 32 * kt];
        }
    }

    // ---------------- final linear + sigmoid (from xf regs, Wf loads shared) ----------------
    float accA = 0.f, accB = 0.f;
    #pragma unroll
    for (int nt = 0; nt < 3; ++nt) {
        int f = 16 * nt + j;
        if (f < F) {
            #pragma unroll
            for (int kt = 0; kt < 2; ++kt) {
                const float* wp = Wf + f * E + 32 * kt + 8 * g;
                float4 wa = *(const float4*)wp;
                float4 wb = *(const float4*)(wp + 4);
                #pragma unroll
                for (int i = 0; i < 4; ++i) {
                    accA += bf2f((ushort)xf[0][nt][kt][i]) * ((const float*)&wa)[i];
                    accB += bf2f((ushort)xf[1][nt][kt][i]) * ((const float*)&wa)[i];
                }
                #pragma unroll
                for (int i = 0; i < 4; ++i) {
                    accA += bf2f((ushort)xf[0][nt][kt][4 + i]) * ((const float*)&wb)[i];
                    accB += bf2f((ushort)xf[1][nt][kt][4 + i]) * ((const float*)&wb)[i];
                }
            }
        }
    }
    #pragma unroll
    for (int off = 1; off < 64; off <<= 1) {
        accA += __shfl_xor(accA, off);
        accB += __shfl_xor(accB, off);
    }
    if (l == 0) {
        out[s0] = 1.f / (1.f + __expf(-(accA + bfin[0])));
        out[s1] = 1.f / (1.f + __expf(-(accB + bfin[0])));
    }
}

extern "C" void kernel_launch(void* const* d_in, const int* in_sizes, int n_in,
                              void* d_out, int out_size, void* d_ws, size_t ws_size,
                              hipStream_t stream) {
    ushort* wsb = (ushort*)d_ws;   // 61440 ushorts = 122880 B of scratch
    cvt_weights<<<240, 256, 0, stream>>>(
        (const float*)d_in[5], (const float*)d_in[6], (const float*)d_in[7],
        (const float*)d_in[8], (const float*)d_in[9], wsb);
    autoint_mfma<<<8192, 64, 0, stream>>>(
        (const float*)d_in[0], (const int*)d_in[1],
        (const float*)d_in[2], (const float*)d_in[3],
        (const float*)d_in[4], wsb,
        (const float*)d_in[10], (const float*)d_in[11],
        (float*)d_out);
}